// Round 17
// baseline (89.302 us; speedup 1.0000x reference)
//
#include <hip/hip_runtime.h>

#define GAT_ALPHA 0.2f
#define INV_N (1.0f / 2048.0f)

typedef float f32x4 __attribute__((ext_vector_type(4)));
typedef __bf16 bf16x8 __attribute__((ext_vector_type(8)));
typedef unsigned short us8 __attribute__((ext_vector_type(8)));

__device__ __forceinline__ unsigned short f2bf(float x) {
  union { float f; unsigned u; } v; v.f = x;
  unsigned r = v.u + 0x7FFFu + ((v.u >> 16) & 1u);   // RNE
  return (unsigned short)(r >> 16);
}
__device__ __forceinline__ float lrelu(float x) {
  return fmaxf(x, 0.f) + GAT_ALPHA * fminf(x, 0.f);
}
__device__ __forceinline__ void lgkm_barrier() {
  asm volatile("s_waitcnt lgkmcnt(0)" ::: "memory");
  __builtin_amdgcn_s_barrier();
  __builtin_amdgcn_sched_barrier(0);
}

// ---------------- k0: Wh = h @ W (f32), s1/s2, WhT in bf16 [b][f][j] ----------------
__global__ __launch_bounds__(256)
void k0_wh(const float* __restrict__ h, const float* __restrict__ W,
           const float* __restrict__ a, unsigned short* __restrict__ WhT,
           float* __restrict__ s1g, float* __restrict__ s2g)
{
  __shared__ float h_s[64][132];
  __shared__ float W_s[128][64];
  __shared__ float wt_s[64][66];
  __shared__ float a_s[128];
  const int t = threadIdx.x;
  const int b = blockIdx.y;
  const int r0 = blockIdx.x * 64;

#pragma unroll
  for (int v = 0; v < 8; ++v) {
    int c = v * 256 + t;
    int k = c >> 4, fo = (c & 15) << 2;
    *(float4*)&W_s[k][fo] = *(const float4*)&W[k * 64 + fo];
  }
#pragma unroll
  for (int v = 0; v < 8; ++v) {
    int c = v * 256 + t;
    int r = c >> 5, ko = (c & 31) << 2;
    *(float4*)&h_s[r][ko] = *(const float4*)&h[((size_t)(b * 2048 + r0 + r)) * 128 + ko];
  }
  if (t < 128) a_s[t] = a[t];
  __syncthreads();

  const int tg = t >> 4;          // 0..15
  const int tf = (t & 15) << 2;   // f base
  float acc[4][4] = {};
#pragma unroll
  for (int k4 = 0; k4 < 32; ++k4) {
    float4 hv[4];
#pragma unroll
    for (int i = 0; i < 4; ++i)
      hv[i] = *(const float4*)&h_s[i * 16 + tg][k4 * 4];
#pragma unroll
    for (int kk = 0; kk < 4; ++kk) {
      float4 wv = *(const float4*)&W_s[k4 * 4 + kk][tf];
#pragma unroll
      for (int i = 0; i < 4; ++i) {
        float hx = ((const float*)&hv[i])[kk];
        acc[i][0] = fmaf(hx, wv.x, acc[i][0]);
        acc[i][1] = fmaf(hx, wv.y, acc[i][1]);
        acc[i][2] = fmaf(hx, wv.z, acc[i][2]);
        acc[i][3] = fmaf(hx, wv.w, acc[i][3]);
      }
    }
  }
#pragma unroll
  for (int i = 0; i < 4; ++i)
#pragma unroll
    for (int j = 0; j < 4; ++j)
      wt_s[tf + j][i * 16 + tg] = acc[i][j];
  __syncthreads();

  if (t < 64) {   // s1/s2 for row r = t (f32 exact)
    float v1 = 0.f, v2 = 0.f;
#pragma unroll 8
    for (int f = 0; f < 64; ++f) {
      float w = wt_s[f][t];
      v1 = fmaf(w, a_s[f], v1);
      v2 = fmaf(w, a_s[64 + f], v2);
    }
    s1g[b * 2048 + r0 + t] = v1;
    s2g[b * 2048 + r0 + t] = v2;
  }
  {  // WhT bf16 write, [b][f][j]
    int f = t >> 2, rb = (t & 3) << 4;
    unsigned short pk[16];
#pragma unroll
    for (int i = 0; i < 16; ++i) pk[i] = f2bf(wt_s[f][rb + i]);
    size_t base = ((size_t)(b * 64 + f)) * 2048 + r0 + rb;
    *(uint4*)&WhT[base]     = *(uint4*)&pk[0];
    *(uint4*)&WhT[base + 8] = *(uint4*)&pk[8];
  }
}

// ---------------- k1: block-per-row (R8 verbatim), denom + bitmask ----------------
// bit convention: word[c*4 + q] bit l  <->  j = c*256 + 4*l + q
__global__ __launch_bounds__(256)
void k1_stats(const int* __restrict__ adj, const float* __restrict__ s1g,
              const float* __restrict__ s2g, float* __restrict__ lrow,
              unsigned long long* __restrict__ gmask)
{
  const int t = threadIdx.x;
  const int l = t & 63, wv = t >> 6;
  const int i = blockIdx.x, b = blockIdx.y;
  const size_t row = (size_t)(b * 2048 + i);

  const int4 a0 = *(const int4*)&adj[row * 2048 + 4 * t];
  const int4 a1 = *(const int4*)&adj[row * 2048 + 1024 + 4 * t];
  const float4 z0 = *(const float4*)&s2g[b * 2048 + 4 * t];
  const float4 z1 = *(const float4*)&s2g[b * 2048 + 1024 + 4 * t];

  unsigned long long m00 = __ballot(a0.x > 0), m01 = __ballot(a0.y > 0);
  unsigned long long m02 = __ballot(a0.z > 0), m03 = __ballot(a0.w > 0);
  unsigned long long m10 = __ballot(a1.x > 0), m11 = __ballot(a1.y > 0);
  unsigned long long m12 = __ballot(a1.z > 0), m13 = __ballot(a1.w > 0);
  if (l == 0) {
    unsigned long long* g = gmask + row * 32;
    ulonglong2 p0; p0.x = m00; p0.y = m01;
    ulonglong2 p1; p1.x = m02; p1.y = m03;
    ulonglong2 p2; p2.x = m10; p2.y = m11;
    ulonglong2 p3; p3.x = m12; p3.y = m13;
    *(ulonglong2*)&g[wv * 4]          = p0;
    *(ulonglong2*)&g[wv * 4 + 2]      = p1;
    *(ulonglong2*)&g[16 + wv * 4]     = p2;
    *(ulonglong2*)&g[16 + wv * 4 + 2] = p3;
  }

  const float s1v = s1g[row];
  float sum = 0.f;
  sum += (a0.x > 0) ? __expf(lrelu(s1v + z0.x)) : 0.f;
  sum += (a0.y > 0) ? __expf(lrelu(s1v + z0.y)) : 0.f;
  sum += (a0.z > 0) ? __expf(lrelu(s1v + z0.z)) : 0.f;
  sum += (a0.w > 0) ? __expf(lrelu(s1v + z0.w)) : 0.f;
  sum += (a1.x > 0) ? __expf(lrelu(s1v + z1.x)) : 0.f;
  sum += (a1.y > 0) ? __expf(lrelu(s1v + z1.y)) : 0.f;
  sum += (a1.z > 0) ? __expf(lrelu(s1v + z1.z)) : 0.f;
  sum += (a1.w > 0) ? __expf(lrelu(s1v + z1.w)) : 0.f;
#pragma unroll
  for (int o = 32; o > 0; o >>= 1) sum += __shfl_xor(sum, o);
  __shared__ float red2[4];
  if (l == 0) red2[wv] = sum;
  __syncthreads();
  if (t == 0) lrow[row] = red2[0] + red2[1] + red2[2] + red2[3];
}

// ---------------- k2y: PV ONLY -> hout (ELU). No att stores, no HBM streams. ----------
// 16-row strips. Recomputes masked-e from gmask (LDS) + s2 (L2). R15-proven loop:
// wave-private wh_s (no barrier), att_s dbuf, ONE lgkm barrier/iter. Unnormalized
// accumulate; scale by il (or 1/N uniform for no-neighbor rows) in epilogue.
__global__ __launch_bounds__(256)
void k2y(const unsigned long long* __restrict__ gmask,
         const unsigned short* __restrict__ WhT,
         const float* __restrict__ s1g, const float* __restrict__ s2g,
         const float* __restrict__ lrow, float* __restrict__ hout)
{
  __shared__ unsigned long long bm_s[16][32];    // 4 KB: full row masks
  __shared__ float s1_s[16], il_s[16];
  __shared__ int uni_s[16];
  __shared__ unsigned short att_s[2][16][136];   // 8.7 KB dbuf
  __shared__ unsigned short wh_s[4][16][136];    // 17.4 KB wave-private

  const int t = threadIdx.x;
  const int b = blockIdx.y;
  const int r0 = blockIdx.x * 16;
  const size_t rowb = (size_t)(b * 2048 + r0);

  {
    const int rr = t >> 4, wq = (t & 15) << 1;
    ulonglong2 v = *(const ulonglong2*)&gmask[(rowb + rr) * 32 + wq];
    bm_s[rr][wq] = v.x; bm_s[rr][wq + 1] = v.y;
  }
  if (t < 16) {
    float L = lrow[rowb + t];
    s1_s[t]  = s1g[rowb + t];
    il_s[t]  = (L > 0.f) ? 1.f / L : INV_N;
    uni_s[t] = (L > 0.f) ? 0 : 1;
  }
  __syncthreads();

  const int r = t >> 4, q = t & 15;
  const int w  = t >> 6, l = t & 63;
  const int ln = l & 15, lg = l >> 4;
  const float s1v = s1_s[r];
  const int runi  = uni_s[r];
  const float* __restrict__ z = s2g + b * 2048;
  const unsigned short* __restrict__ wsrc =
      WhT + ((size_t)(b * 64 + w * 16)) * 2048;

  f32x4 acc = {0.f, 0.f, 0.f, 0.f};
  int p = 0;

  for (int j0 = 0; j0 < 2048; j0 += 128) {
    // wave-private Wh loads (T14 same-iter, proven)
    uint4 wreg[4];
#pragma unroll
    for (int v = 0; v < 4; ++v)
      wreg[v] = *(const uint4*)&wsrc[(size_t)(v * 4 + lg) * 2048 + j0 + ln * 8];

    // masked-e (unnormalized) for row r, j = j0 + q*8 .. +8
    const int jb = j0 + q * 8;
    const int c4 = (jb >> 8) << 2;
    const int l0 = (jb >> 2) & 63;
    const unsigned long long w0 = bm_s[r][c4 + 0];
    const unsigned long long w1 = bm_s[r][c4 + 1];
    const unsigned long long w2 = bm_s[r][c4 + 2];
    const unsigned long long w3 = bm_s[r][c4 + 3];
    const float4 z0v = *(const float4*)&z[jb];
    const float4 z1v = *(const float4*)&z[jb + 4];
    us8 pk;
#define PE(m, wq, sh, zz)                                          \
    { const bool on = ((wq >> (sh)) & 1ull) != 0;                  \
      float e = runi ? 1.f                                         \
                     : (on ? __expf(lrelu(s1v + (zz))) : 0.f);     \
      pk[m] = f2bf(e); }
    PE(0, w0, l0, z0v.x)     PE(1, w1, l0, z0v.y)
    PE(2, w2, l0, z0v.z)     PE(3, w3, l0, z0v.w)
    PE(4, w0, l0 + 1, z1v.x) PE(5, w1, l0 + 1, z1v.y)
    PE(6, w2, l0 + 1, z1v.z) PE(7, w3, l0 + 1, z1v.w)
#undef PE
    *(us8*)&att_s[p][r][q * 8] = pk;
    // wave-private wh_s write (intra-wave lgkm ordering; no barrier needed)
#pragma unroll
    for (int v = 0; v < 4; ++v)
      *(uint4*)&wh_s[w][v * 4 + lg][ln * 8] = wreg[v];

    lgkm_barrier();   // publish att_s[p]
#pragma unroll
    for (int ks = 0; ks < 4; ++ks) {
      union { us8 u; bf16x8 v; } ac, bc;
      ac.u = *(const us8*)&att_s[p][ln][ks * 32 + lg * 8];
      bc.u = *(const us8*)&wh_s[w][ln][ks * 32 + lg * 8];
      acc = __builtin_amdgcn_mfma_f32_16x16x32_bf16(ac.v, bc.v, acc, 0, 0, 0);
    }
    p ^= 1;
  }

  // epilogue: scale + ELU. C/D layout: col(N=f)=lane&15, row(M)=4*(lane>>4)+reg
#pragma unroll
  for (int qq = 0; qq < 4; ++qq) {
    const int rr = lg * 4 + qq;
    const float x = acc[qq] * il_s[rr];
    hout[(rowb + rr) * 64 + w * 16 + ln] = (x > 0.f) ? x : expm1f(x);
  }
}

// ---------------- k2_att: PURE att store stream (no MFMA, no loop barriers) ----------
// 8-row strips, 2048 blocks, 2.3 KB LDS -> high occupancy. Per thread-iter:
// 1 L2 zv load, 4 mask bits (LDS broadcast), 4 exp, 1 nt f32x4 store.
__global__ __launch_bounds__(256)
void k2_att(const unsigned long long* __restrict__ gmask,
            const float* __restrict__ s1g, const float* __restrict__ s2g,
            const float* __restrict__ lrow, float* __restrict__ att)
{
  __shared__ unsigned long long bm_s[8][32];   // 2 KB
  __shared__ float s1_s[8], il_s[8];

  const int t = threadIdx.x;
  const int b = blockIdx.y;
  const int r0 = blockIdx.x * 8;
  const size_t rowb = (size_t)(b * 2048 + r0);

  bm_s[t >> 5][t & 31] = gmask[(rowb + (t >> 5)) * 32 + (t & 31)];
  if (t < 8) {
    float L = lrow[rowb + t];
    s1_s[t] = s1g[rowb + t];
    il_s[t] = (L > 0.f) ? 1.f / L : -1.f;
  }
  __syncthreads();

  const int rslot = t >> 5;            // row 0..7
  const int jpos = (t & 31) << 2;
  const float s1r = s1_s[rslot];
  const float il  = il_s[rslot];
  const bool uni  = (il < 0.f);
  const float* __restrict__ z = s2g + b * 2048;
  float* __restrict__ arow = att + (rowb + rslot) * 2048;

  for (int j0 = 0; j0 < 2048; j0 += 128) {
    const int j = j0 + jpos;
    const int lc4 = (j >> 8) << 2;
    const int pos = (j & 255) >> 2;
    const unsigned long long w0 = bm_s[rslot][lc4 + 0];
    const unsigned long long w1 = bm_s[rslot][lc4 + 1];
    const unsigned long long w2 = bm_s[rslot][lc4 + 2];
    const unsigned long long w3 = bm_s[rslot][lc4 + 3];
    const float4 zv = *(const float4*)&z[j];
    f32x4 o;
#define PW(dst, zz, wq)                                             \
    { float e = __expf(lrelu(s1r + (zz))) * il;                     \
      dst = uni ? INV_N : ((((wq) >> pos) & 1ull) ? e : 0.f); }
    PW(o[0], zv.x, w0) PW(o[1], zv.y, w1) PW(o[2], zv.z, w2) PW(o[3], zv.w, w3)
#undef PW
    __builtin_nontemporal_store(o, (f32x4*)&arow[j]);
  }
}

extern "C" void kernel_launch(void* const* d_in, const int* in_sizes, int n_in,
                              void* d_out, int out_size, void* d_ws, size_t ws_size,
                              hipStream_t stream)
{
  const float* h   = (const float*)d_in[0];
  const int*   adj = (const int*)d_in[1];
  const float* W   = (const float*)d_in[2];
  const float* a   = (const float*)d_in[3];
  float* hout = (float*)d_out;
  float* att  = hout + (size_t)8 * 2048 * 64;

  char* ws = (char*)d_ws;
  unsigned short* WhT = (unsigned short*)ws;                    // 2 MB
  float* s1 = (float*)(ws + (size_t)(2u << 20));                // 64 KB each
  float* s2 = s1 + 16384;
  float* lr = s2 + 16384;
  unsigned long long* gmask =
      (unsigned long long*)(ws + (size_t)(2u << 20) + 3 * 65536); // 4 MB

  k0_wh   <<<dim3(32, 8),   256, 0, stream>>>(h, W, a, WhT, s1, s2);
  k1_stats<<<dim3(2048, 8), 256, 0, stream>>>(adj, s1, s2, lr, gmask);
  k2y     <<<dim3(128, 8),  256, 0, stream>>>(gmask, WhT, s1, s2, lr, hout);
  k2_att  <<<dim3(256, 8),  256, 0, stream>>>(gmask, s1, s2, lr, att);
}

// Round 18
// 86.504 us; speedup vs baseline: 1.0323x; 1.0323x over previous
//
#include <hip/hip_runtime.h>

#define GAT_ALPHA 0.2f
#define INV_N (1.0f / 2048.0f)

typedef float f32x4 __attribute__((ext_vector_type(4)));
typedef __bf16 bf16x8 __attribute__((ext_vector_type(8)));
typedef unsigned short us8 __attribute__((ext_vector_type(8)));
typedef unsigned short us4 __attribute__((ext_vector_type(4)));

__device__ __forceinline__ unsigned short f2bf(float x) {
  union { float f; unsigned u; } v; v.f = x;
  unsigned r = v.u + 0x7FFFu + ((v.u >> 16) & 1u);   // RNE
  return (unsigned short)(r >> 16);
}
__device__ __forceinline__ float lrelu(float x) {
  return fmaxf(x, 0.f) + GAT_ALPHA * fminf(x, 0.f);
}
__device__ __forceinline__ void lgkm_barrier() {
  asm volatile("s_waitcnt lgkmcnt(0)" ::: "memory");
  __builtin_amdgcn_s_barrier();
  __builtin_amdgcn_sched_barrier(0);
}

// ---------------- k0: Wh = h @ W (f32), s1/s2, WhT in bf16 [b][f][j] ----------------
__global__ __launch_bounds__(256)
void k0_wh(const float* __restrict__ h, const float* __restrict__ W,
           const float* __restrict__ a, unsigned short* __restrict__ WhT,
           float* __restrict__ s1g, float* __restrict__ s2g)
{
  __shared__ float h_s[64][132];
  __shared__ float W_s[128][64];
  __shared__ float wt_s[64][66];
  __shared__ float a_s[128];
  const int t = threadIdx.x;
  const int b = blockIdx.y;
  const int r0 = blockIdx.x * 64;

#pragma unroll
  for (int v = 0; v < 8; ++v) {
    int c = v * 256 + t;
    int k = c >> 4, fo = (c & 15) << 2;
    *(float4*)&W_s[k][fo] = *(const float4*)&W[k * 64 + fo];
  }
#pragma unroll
  for (int v = 0; v < 8; ++v) {
    int c = v * 256 + t;
    int r = c >> 5, ko = (c & 31) << 2;
    *(float4*)&h_s[r][ko] = *(const float4*)&h[((size_t)(b * 2048 + r0 + r)) * 128 + ko];
  }
  if (t < 128) a_s[t] = a[t];
  __syncthreads();

  const int tg = t >> 4;          // 0..15
  const int tf = (t & 15) << 2;   // f base
  float acc[4][4] = {};
#pragma unroll
  for (int k4 = 0; k4 < 32; ++k4) {
    float4 hv[4];
#pragma unroll
    for (int i = 0; i < 4; ++i)
      hv[i] = *(const float4*)&h_s[i * 16 + tg][k4 * 4];
#pragma unroll
    for (int kk = 0; kk < 4; ++kk) {
      float4 wv = *(const float4*)&W_s[k4 * 4 + kk][tf];
#pragma unroll
      for (int i = 0; i < 4; ++i) {
        float hx = ((const float*)&hv[i])[kk];
        acc[i][0] = fmaf(hx, wv.x, acc[i][0]);
        acc[i][1] = fmaf(hx, wv.y, acc[i][1]);
        acc[i][2] = fmaf(hx, wv.z, acc[i][2]);
        acc[i][3] = fmaf(hx, wv.w, acc[i][3]);
      }
    }
  }
#pragma unroll
  for (int i = 0; i < 4; ++i)
#pragma unroll
    for (int j = 0; j < 4; ++j)
      wt_s[tf + j][i * 16 + tg] = acc[i][j];
  __syncthreads();

  if (t < 64) {   // s1/s2 for row r = t (f32 exact)
    float v1 = 0.f, v2 = 0.f;
#pragma unroll 8
    for (int f = 0; f < 64; ++f) {
      float w = wt_s[f][t];
      v1 = fmaf(w, a_s[f], v1);
      v2 = fmaf(w, a_s[64 + f], v2);
    }
    s1g[b * 2048 + r0 + t] = v1;
    s2g[b * 2048 + r0 + t] = v2;
  }
  {  // WhT bf16 write, [b][f][j]
    int f = t >> 2, rb = (t & 3) << 4;
    unsigned short pk[16];
#pragma unroll
    for (int i = 0; i < 16; ++i) pk[i] = f2bf(wt_s[f][rb + i]);
    size_t base = ((size_t)(b * 64 + f)) * 2048 + r0 + rb;
    *(uint4*)&WhT[base]     = *(uint4*)&pk[0];
    *(uint4*)&WhT[base + 8] = *(uint4*)&pk[8];
  }
}

// ---------------- k1: block-per-row (R8 verbatim), denom + bitmask ----------------
// bit convention: word[c*4 + q] bit l  <->  j = c*256 + 4*l + q
__global__ __launch_bounds__(256)
void k1_stats(const int* __restrict__ adj, const float* __restrict__ s1g,
              const float* __restrict__ s2g, float* __restrict__ lrow,
              unsigned long long* __restrict__ gmask)
{
  const int t = threadIdx.x;
  const int l = t & 63, wv = t >> 6;
  const int i = blockIdx.x, b = blockIdx.y;
  const size_t row = (size_t)(b * 2048 + i);

  const int4 a0 = *(const int4*)&adj[row * 2048 + 4 * t];
  const int4 a1 = *(const int4*)&adj[row * 2048 + 1024 + 4 * t];
  const float4 z0 = *(const float4*)&s2g[b * 2048 + 4 * t];
  const float4 z1 = *(const float4*)&s2g[b * 2048 + 1024 + 4 * t];

  unsigned long long m00 = __ballot(a0.x > 0), m01 = __ballot(a0.y > 0);
  unsigned long long m02 = __ballot(a0.z > 0), m03 = __ballot(a0.w > 0);
  unsigned long long m10 = __ballot(a1.x > 0), m11 = __ballot(a1.y > 0);
  unsigned long long m12 = __ballot(a1.z > 0), m13 = __ballot(a1.w > 0);
  if (l == 0) {
    unsigned long long* g = gmask + row * 32;
    ulonglong2 p0; p0.x = m00; p0.y = m01;
    ulonglong2 p1; p1.x = m02; p1.y = m03;
    ulonglong2 p2; p2.x = m10; p2.y = m11;
    ulonglong2 p3; p3.x = m12; p3.y = m13;
    *(ulonglong2*)&g[wv * 4]          = p0;
    *(ulonglong2*)&g[wv * 4 + 2]      = p1;
    *(ulonglong2*)&g[16 + wv * 4]     = p2;
    *(ulonglong2*)&g[16 + wv * 4 + 2] = p3;
  }

  const float s1v = s1g[row];
  float sum = 0.f;
  sum += (a0.x > 0) ? __expf(lrelu(s1v + z0.x)) : 0.f;
  sum += (a0.y > 0) ? __expf(lrelu(s1v + z0.y)) : 0.f;
  sum += (a0.z > 0) ? __expf(lrelu(s1v + z0.z)) : 0.f;
  sum += (a0.w > 0) ? __expf(lrelu(s1v + z0.w)) : 0.f;
  sum += (a1.x > 0) ? __expf(lrelu(s1v + z1.x)) : 0.f;
  sum += (a1.y > 0) ? __expf(lrelu(s1v + z1.y)) : 0.f;
  sum += (a1.z > 0) ? __expf(lrelu(s1v + z1.z)) : 0.f;
  sum += (a1.w > 0) ? __expf(lrelu(s1v + z1.w)) : 0.f;
#pragma unroll
  for (int o = 32; o > 0; o >>= 1) sum += __shfl_xor(sum, o);
  __shared__ float red2[4];
  if (l == 0) red2[wv] = sum;
  __syncthreads();
  if (t == 0) lrow[row] = red2[0] + red2[1] + red2[2] + red2[3];
}

// ---------------- k2: R15 structure, LDS diet: no bm_s (gmask via L2 broadcast) ----
// 16-row strips, wave-private wh_s (no barrier), att_s dbuf, ONE lgkm barrier/iter.
// LDS 25.6 KB -> 6 blocks/CU (24 waves/CU, was 4-5). No launch-bounds clamp.
__global__ __launch_bounds__(256)
void k2_att_pv(const unsigned long long* __restrict__ gmask,
               const unsigned short* __restrict__ WhT,
               const float* __restrict__ s1g, const float* __restrict__ s2g,
               const float* __restrict__ lrow,
               float* __restrict__ pp0, float* __restrict__ pp1,
               float* __restrict__ att)
{
  __shared__ float s1_s[16], il_s[16];
  __shared__ unsigned short att_s[2][16][136];    // 8.7 KB dbuf
  __shared__ unsigned short wh_s[4][16][136];     // 17.4 KB, per-wave regions

  const int t = threadIdx.x;
  const int b = blockIdx.z;
  const int jh = blockIdx.y;
  const int jb = jh << 10;
  const int r0 = blockIdx.x * 16;
  const size_t rowb = (size_t)(b * 2048 + r0);

  if (t < 16) {
    float L = lrow[rowb + t];
    s1_s[t] = s1g[rowb + t];
    il_s[t] = (L > 0.f) ? 1.f / L : -1.f;   // -1 sentinel: no neighbors -> uniform 1/N
  }
  __syncthreads();

  const int w  = t >> 6, l = t & 63;
  const int ln = l & 15, lg = l >> 4;
  const int jj = (t & 31) << 2;
  const int rbase = (t >> 5) & 7;
  const unsigned short* __restrict__ wsrc =
      WhT + ((size_t)(b * 64 + w * 16)) * 2048;
  f32x4 acc = {0.f, 0.f, 0.f, 0.f};

  int p = 0;
  for (int j0 = jb; j0 < jb + 1024; j0 += 128) {
    // T14 (same-iter): issue this wave's wh loads early
    uint4 wreg[4];
#pragma unroll
    for (int v = 0; v < 4; ++v)
      wreg[v] = *(const uint4*)&wsrc[(size_t)(v * 4 + lg) * 2048 + j0 + ln * 8];

    // attention: 16 rows x 128 j; 8 elems/thread (rows rbase, rbase+8)
    const int j = j0 + jj;
    const float4 zv = *(const float4*)&s2g[b * 2048 + j];
    const int lc4 = ((j >> 8) & 3) << 2;
    const int pos = (j & 255) >> 2;
#pragma unroll
    for (int it = 0; it < 2; ++it) {
      const int rr = rbase + (it << 3);
      // mask words straight from L2 (32 B broadcast per 32-thread group)
      const unsigned long long* __restrict__ gm =
          gmask + (rowb + rr) * 32 + jh * 16 + lc4;
      ulonglong2 u0 = *(const ulonglong2*)&gm[0];
      ulonglong2 u1 = *(const ulonglong2*)&gm[2];
      const float s1r = s1_s[rr], il = il_s[rr];
      const bool uni = (il < 0.f);
      f32x4 o;
#define PW(dst, zz, wq)                                             \
      { float e = __expf(lrelu(s1r + (zz))) * il;                   \
        dst = uni ? INV_N : ((((wq) >> pos) & 1ull) ? e : 0.f); }
      PW(o[0], zv.x, u0.x) PW(o[1], zv.y, u0.y)
      PW(o[2], zv.z, u1.x) PW(o[3], zv.w, u1.y)
#undef PW
      __builtin_nontemporal_store(o, (f32x4*)&att[(rowb + rr) * 2048 + j]);
      us4 pk;
      pk.x = f2bf(o[0]); pk.y = f2bf(o[1]); pk.z = f2bf(o[2]); pk.w = f2bf(o[3]);
      *(us4*)&att_s[p][rr][jj] = pk;
    }
    // wave-private wh_s write (intra-wave lgkm ordering; no barrier needed)
#pragma unroll
    for (int v = 0; v < 4; ++v)
      *(uint4*)&wh_s[w][v * 4 + lg][ln * 8] = wreg[v];

    lgkm_barrier();   // publish att_s[p]; nt stores NOT drained
    // PV: A from att_s[p], B from own wh_s region (same k-permutation)
#pragma unroll
    for (int ks = 0; ks < 4; ++ks) {
      union { us8 u; bf16x8 v; } ac, bc;
      ac.u = *(const us8*)&att_s[p][ln][ks * 32 + lg * 8];
      bc.u = *(const us8*)&wh_s[w][ln][ks * 32 + lg * 8];
      acc = __builtin_amdgcn_mfma_f32_16x16x32_bf16(ac.v, bc.v, acc, 0, 0, 0);
    }
    p ^= 1;
  }

  // partial write. C/D layout: col(N=f)=lane&15, row(M)=4*(lane>>4)+reg
  float* __restrict__ pp = (jh == 0) ? pp0 : pp1;
#pragma unroll
  for (int q = 0; q < 4; ++q) {
    const int rr = lg * 4 + q;
    pp[(rowb + rr) * 64 + w * 16 + ln] = acc[q];
  }
}

// ---------------- k3: hout = elu(pp0 + pp1) ----------------
__global__ __launch_bounds__(256)
void k3_elu(const float* __restrict__ pp0, const float* __restrict__ pp1,
            float* __restrict__ hout)
{
  const size_t idx = ((size_t)blockIdx.x * 256 + threadIdx.x) * 4;
  float4 a = *(const float4*)&pp0[idx];
  float4 c = *(const float4*)&pp1[idx];
  float4 o;
  float x;
  x = a.x + c.x; o.x = (x > 0.f) ? x : expm1f(x);
  x = a.y + c.y; o.y = (x > 0.f) ? x : expm1f(x);
  x = a.z + c.z; o.z = (x > 0.f) ? x : expm1f(x);
  x = a.w + c.w; o.w = (x > 0.f) ? x : expm1f(x);
  *(float4*)&hout[idx] = o;
}

extern "C" void kernel_launch(void* const* d_in, const int* in_sizes, int n_in,
                              void* d_out, int out_size, void* d_ws, size_t ws_size,
                              hipStream_t stream)
{
  const float* h   = (const float*)d_in[0];
  const int*   adj = (const int*)d_in[1];
  const float* W   = (const float*)d_in[2];
  const float* a   = (const float*)d_in[3];
  float* hout = (float*)d_out;
  float* att  = hout + (size_t)8 * 2048 * 64;

  char* ws = (char*)d_ws;
  unsigned short* WhT = (unsigned short*)ws;                    // 2 MB
  float* s1 = (float*)(ws + (size_t)(2u << 20));                // 64 KB each
  float* s2 = s1 + 16384;
  float* lr = s2 + 16384;
  unsigned long long* gmask =
      (unsigned long long*)(ws + (size_t)(2u << 20) + 3 * 65536); // 4 MB
  float* pp0 = (float*)(ws + (size_t)(2u << 20) + 3 * 65536 + (4u << 20)); // 4 MB
  float* pp1 = pp0 + (size_t)8 * 2048 * 64;                                // 4 MB

  k0_wh    <<<dim3(32, 8),     256, 0, stream>>>(h, W, a, WhT, s1, s2);
  k1_stats <<<dim3(2048, 8),   256, 0, stream>>>(adj, s1, s2, lr, gmask);
  k2_att_pv<<<dim3(128, 2, 8), 256, 0, stream>>>(gmask, WhT, s1, s2, lr, pp0, pp1, att);
  k3_elu   <<<dim3(1024),      256, 0, stream>>>(pp0, pp1, hout);
}

// Round 19
// 73.283 us; speedup vs baseline: 1.2186x; 1.1804x over previous
//
#include <hip/hip_runtime.h>

#define GAT_ALPHA 0.2f
#define INV_N (1.0f / 2048.0f)

typedef float f32x4 __attribute__((ext_vector_type(4)));
typedef __bf16 bf16x8 __attribute__((ext_vector_type(8)));
typedef unsigned short us8 __attribute__((ext_vector_type(8)));
typedef unsigned short us4 __attribute__((ext_vector_type(4)));

__device__ __forceinline__ unsigned short f2bf(float x) {
  union { float f; unsigned u; } v; v.f = x;
  unsigned r = v.u + 0x7FFFu + ((v.u >> 16) & 1u);   // RNE
  return (unsigned short)(r >> 16);
}
__device__ __forceinline__ float lrelu(float x) {
  return fmaxf(x, 0.f) + GAT_ALPHA * fminf(x, 0.f);
}
__device__ __forceinline__ void lgkm_barrier() {
  asm volatile("s_waitcnt lgkmcnt(0)" ::: "memory");
  __builtin_amdgcn_s_barrier();
  __builtin_amdgcn_sched_barrier(0);
}

// ---------------- k0: Wh = h @ W (f32), s1/s2, WhT in bf16 [b][f][j] ----------------
__global__ __launch_bounds__(256)
void k0_wh(const float* __restrict__ h, const float* __restrict__ W,
           const float* __restrict__ a, unsigned short* __restrict__ WhT,
           float* __restrict__ s1g, float* __restrict__ s2g)
{
  __shared__ float h_s[64][132];
  __shared__ float W_s[128][64];
  __shared__ float wt_s[64][66];
  __shared__ float a_s[128];
  const int t = threadIdx.x;
  const int b = blockIdx.y;
  const int r0 = blockIdx.x * 64;

#pragma unroll
  for (int v = 0; v < 8; ++v) {
    int c = v * 256 + t;
    int k = c >> 4, fo = (c & 15) << 2;
    *(float4*)&W_s[k][fo] = *(const float4*)&W[k * 64 + fo];
  }
#pragma unroll
  for (int v = 0; v < 8; ++v) {
    int c = v * 256 + t;
    int r = c >> 5, ko = (c & 31) << 2;
    *(float4*)&h_s[r][ko] = *(const float4*)&h[((size_t)(b * 2048 + r0 + r)) * 128 + ko];
  }
  if (t < 128) a_s[t] = a[t];
  __syncthreads();

  const int tg = t >> 4;          // 0..15
  const int tf = (t & 15) << 2;   // f base
  float acc[4][4] = {};
#pragma unroll
  for (int k4 = 0; k4 < 32; ++k4) {
    float4 hv[4];
#pragma unroll
    for (int i = 0; i < 4; ++i)
      hv[i] = *(const float4*)&h_s[i * 16 + tg][k4 * 4];
#pragma unroll
    for (int kk = 0; kk < 4; ++kk) {
      float4 wv = *(const float4*)&W_s[k4 * 4 + kk][tf];
#pragma unroll
      for (int i = 0; i < 4; ++i) {
        float hx = ((const float*)&hv[i])[kk];
        acc[i][0] = fmaf(hx, wv.x, acc[i][0]);
        acc[i][1] = fmaf(hx, wv.y, acc[i][1]);
        acc[i][2] = fmaf(hx, wv.z, acc[i][2]);
        acc[i][3] = fmaf(hx, wv.w, acc[i][3]);
      }
    }
  }
#pragma unroll
  for (int i = 0; i < 4; ++i)
#pragma unroll
    for (int j = 0; j < 4; ++j)
      wt_s[tf + j][i * 16 + tg] = acc[i][j];
  __syncthreads();

  if (t < 64) {   // s1/s2 for row r = t (f32 exact)
    float v1 = 0.f, v2 = 0.f;
#pragma unroll 8
    for (int f = 0; f < 64; ++f) {
      float w = wt_s[f][t];
      v1 = fmaf(w, a_s[f], v1);
      v2 = fmaf(w, a_s[64 + f], v2);
    }
    s1g[b * 2048 + r0 + t] = v1;
    s2g[b * 2048 + r0 + t] = v2;
  }
  {  // WhT bf16 write, [b][f][j]
    int f = t >> 2, rb = (t & 3) << 4;
    unsigned short pk[16];
#pragma unroll
    for (int i = 0; i < 16; ++i) pk[i] = f2bf(wt_s[f][rb + i]);
    size_t base = ((size_t)(b * 64 + f)) * 2048 + r0 + rb;
    *(uint4*)&WhT[base]     = *(uint4*)&pk[0];
    *(uint4*)&WhT[base + 8] = *(uint4*)&pk[8];
  }
}

// ---------------- k1: block-per-row (R8 verbatim), denom + bitmask ----------------
// bit convention: word[c*4 + q] bit l  <->  j = c*256 + 4*l + q
__global__ __launch_bounds__(256)
void k1_stats(const int* __restrict__ adj, const float* __restrict__ s1g,
              const float* __restrict__ s2g, float* __restrict__ lrow,
              unsigned long long* __restrict__ gmask)
{
  const int t = threadIdx.x;
  const int l = t & 63, wv = t >> 6;
  const int i = blockIdx.x, b = blockIdx.y;
  const size_t row = (size_t)(b * 2048 + i);

  const int4 a0 = *(const int4*)&adj[row * 2048 + 4 * t];
  const int4 a1 = *(const int4*)&adj[row * 2048 + 1024 + 4 * t];
  const float4 z0 = *(const float4*)&s2g[b * 2048 + 4 * t];
  const float4 z1 = *(const float4*)&s2g[b * 2048 + 1024 + 4 * t];

  unsigned long long m00 = __ballot(a0.x > 0), m01 = __ballot(a0.y > 0);
  unsigned long long m02 = __ballot(a0.z > 0), m03 = __ballot(a0.w > 0);
  unsigned long long m10 = __ballot(a1.x > 0), m11 = __ballot(a1.y > 0);
  unsigned long long m12 = __ballot(a1.z > 0), m13 = __ballot(a1.w > 0);
  if (l == 0) {
    unsigned long long* g = gmask + row * 32;
    ulonglong2 p0; p0.x = m00; p0.y = m01;
    ulonglong2 p1; p1.x = m02; p1.y = m03;
    ulonglong2 p2; p2.x = m10; p2.y = m11;
    ulonglong2 p3; p3.x = m12; p3.y = m13;
    *(ulonglong2*)&g[wv * 4]          = p0;
    *(ulonglong2*)&g[wv * 4 + 2]      = p1;
    *(ulonglong2*)&g[16 + wv * 4]     = p2;
    *(ulonglong2*)&g[16 + wv * 4 + 2] = p3;
  }

  const float s1v = s1g[row];
  float sum = 0.f;
  sum += (a0.x > 0) ? __expf(lrelu(s1v + z0.x)) : 0.f;
  sum += (a0.y > 0) ? __expf(lrelu(s1v + z0.y)) : 0.f;
  sum += (a0.z > 0) ? __expf(lrelu(s1v + z0.z)) : 0.f;
  sum += (a0.w > 0) ? __expf(lrelu(s1v + z0.w)) : 0.f;
  sum += (a1.x > 0) ? __expf(lrelu(s1v + z1.x)) : 0.f;
  sum += (a1.y > 0) ? __expf(lrelu(s1v + z1.y)) : 0.f;
  sum += (a1.z > 0) ? __expf(lrelu(s1v + z1.z)) : 0.f;
  sum += (a1.w > 0) ? __expf(lrelu(s1v + z1.w)) : 0.f;
#pragma unroll
  for (int o = 32; o > 0; o >>= 1) sum += __shfl_xor(sum, o);
  __shared__ float red2[4];
  if (l == 0) red2[wv] = sum;
  __syncthreads();
  if (t == 0) lrow[row] = red2[0] + red2[1] + red2[2] + red2[3];
}

// ---------------- k2: att write (nt) + partial PV; 16-row strips, wave-private wh_s,
//                  att_s double-buffered -> ONE lgkm barrier per iter ----------------
// Wave w owns f-tile w (16 f). wh_s[w] is PRIVATE to wave w (staged global->reg->
// ds_write, ordered by intra-wave lgkmcnt -> needs NO barrier). att_s[2] dbuf:
// writes to p^1 never collide with in-flight reads of p (slow wave's reads are
// complete before it passes the barrier -> reuse is safe).
__global__ __launch_bounds__(256)
void k2_att_pv(const unsigned long long* __restrict__ gmask,
               const unsigned short* __restrict__ WhT,
               const float* __restrict__ s1g, const float* __restrict__ s2g,
               const float* __restrict__ lrow,
               float* __restrict__ pp0, float* __restrict__ pp1,
               float* __restrict__ att)
{
  __shared__ unsigned long long bm_s[16][16];     // 2 KB (jh half: 16 words/row)
  __shared__ float s1_s[16], il_s[16];
  __shared__ unsigned short att_s[2][16][136];    // 8.7 KB dbuf
  __shared__ unsigned short wh_s[4][16][136];     // 17.4 KB, per-wave regions

  const int t = threadIdx.x;
  const int b = blockIdx.z;
  const int jh = blockIdx.y;
  const int jb = jh << 10;
  const int r0 = blockIdx.x * 16;
  const size_t rowb = (size_t)(b * 2048 + r0);

  bm_s[t >> 4][t & 15] = gmask[(rowb + (t >> 4)) * 32 + jh * 16 + (t & 15)];
  if (t < 16) {
    float L = lrow[rowb + t];
    s1_s[t] = s1g[rowb + t];
    il_s[t] = (L > 0.f) ? 1.f / L : -1.f;   // -1 sentinel: no neighbors -> uniform 1/N
  }
  __syncthreads();

  const int w  = t >> 6, l = t & 63;
  const int ln = l & 15, lg = l >> 4;
  const int jj = (t & 31) << 2;
  const int rbase = (t >> 5) & 7;
  // wh staging: load v covers rows w*16 + v*4 + lg, bytes ln*16 (fully coalesced)
  const unsigned short* __restrict__ wsrc =
      WhT + ((size_t)(b * 64 + w * 16)) * 2048;
  f32x4 acc = {0.f, 0.f, 0.f, 0.f};

  int p = 0;
  for (int j0 = jb; j0 < jb + 1024; j0 += 128) {
    // T14 (same-iter): issue this wave's wh loads early
    uint4 wreg[4];
#pragma unroll
    for (int v = 0; v < 4; ++v)
      wreg[v] = *(const uint4*)&wsrc[(size_t)(v * 4 + lg) * 2048 + j0 + ln * 8];

    // attention: 16 rows x 128 j; 8 elems/thread (rows rbase, rbase+8)
    const int j = j0 + jj;
    const float4 zv = *(const float4*)&s2g[b * 2048 + j];
    const int lc4 = ((j >> 8) & 3) << 2;
    const int pos = (j & 255) >> 2;
#pragma unroll
    for (int it = 0; it < 2; ++it) {
      const int rr = rbase + (it << 3);
      const float s1r = s1_s[rr], il = il_s[rr];
      const bool uni = (il < 0.f);
      const unsigned long long w0 = bm_s[rr][lc4 + 0];
      const unsigned long long w1 = bm_s[rr][lc4 + 1];
      const unsigned long long w2 = bm_s[rr][lc4 + 2];
      const unsigned long long w3 = bm_s[rr][lc4 + 3];
      f32x4 o;
#define PW(dst, zz, wq)                                             \
      { float e = __expf(lrelu(s1r + (zz))) * il;                   \
        dst = uni ? INV_N : ((((wq) >> pos) & 1ull) ? e : 0.f); }
      PW(o[0], zv.x, w0) PW(o[1], zv.y, w1) PW(o[2], zv.z, w2) PW(o[3], zv.w, w3)
#undef PW
      __builtin_nontemporal_store(o, (f32x4*)&att[(rowb + rr) * 2048 + j]);
      us4 pk;
      pk.x = f2bf(o[0]); pk.y = f2bf(o[1]); pk.z = f2bf(o[2]); pk.w = f2bf(o[3]);
      *(us4*)&att_s[p][rr][jj] = pk;
    }
    // wave-private wh_s write (intra-wave lgkm ordering; no barrier needed)
#pragma unroll
    for (int v = 0; v < 4; ++v)
      *(uint4*)&wh_s[w][v * 4 + lg][ln * 8] = wreg[v];

    lgkm_barrier();   // publish att_s[p]; nt stores NOT drained
    // PV: A from att_s[p], B from own wh_s region (same k-permutation)
#pragma unroll
    for (int ks = 0; ks < 4; ++ks) {
      union { us8 u; bf16x8 v; } ac, bc;
      ac.u = *(const us8*)&att_s[p][ln][ks * 32 + lg * 8];
      bc.u = *(const us8*)&wh_s[w][ln][ks * 32 + lg * 8];
      acc = __builtin_amdgcn_mfma_f32_16x16x32_bf16(ac.v, bc.v, acc, 0, 0, 0);
    }
    p ^= 1;
  }

  // partial write. C/D layout: col(N=f)=lane&15, row(M)=4*(lane>>4)+reg
  float* __restrict__ pp = (jh == 0) ? pp0 : pp1;
#pragma unroll
  for (int q = 0; q < 4; ++q) {
    const int rr = lg * 4 + q;
    pp[(rowb + rr) * 64 + w * 16 + ln] = acc[q];
  }
}

// ---------------- k3: hout = elu(pp0 + pp1) ----------------
__global__ __launch_bounds__(256)
void k3_elu(const float* __restrict__ pp0, const float* __restrict__ pp1,
            float* __restrict__ hout)
{
  const size_t idx = ((size_t)blockIdx.x * 256 + threadIdx.x) * 4;
  float4 a = *(const float4*)&pp0[idx];
  float4 c = *(const float4*)&pp1[idx];
  float4 o;
  float x;
  x = a.x + c.x; o.x = (x > 0.f) ? x : expm1f(x);
  x = a.y + c.y; o.y = (x > 0.f) ? x : expm1f(x);
  x = a.z + c.z; o.z = (x > 0.f) ? x : expm1f(x);
  x = a.w + c.w; o.w = (x > 0.f) ? x : expm1f(x);
  *(float4*)&hout[idx] = o;
}

extern "C" void kernel_launch(void* const* d_in, const int* in_sizes, int n_in,
                              void* d_out, int out_size, void* d_ws, size_t ws_size,
                              hipStream_t stream)
{
  const float* h   = (const float*)d_in[0];
  const int*   adj = (const int*)d_in[1];
  const float* W   = (const float*)d_in[2];
  const float* a   = (const float*)d_in[3];
  float* hout = (float*)d_out;
  float* att  = hout + (size_t)8 * 2048 * 64;

  char* ws = (char*)d_ws;
  unsigned short* WhT = (unsigned short*)ws;                    // 2 MB
  float* s1 = (float*)(ws + (size_t)(2u << 20));                // 64 KB each
  float* s2 = s1 + 16384;
  float* lr = s2 + 16384;
  unsigned long long* gmask =
      (unsigned long long*)(ws + (size_t)(2u << 20) + 3 * 65536); // 4 MB
  float* pp0 = (float*)(ws + (size_t)(2u << 20) + 3 * 65536 + (4u << 20)); // 4 MB
  float* pp1 = pp0 + (size_t)8 * 2048 * 64;                                // 4 MB

  k0_wh    <<<dim3(32, 8),     256, 0, stream>>>(h, W, a, WhT, s1, s2);
  k1_stats <<<dim3(2048, 8),   256, 0, stream>>>(adj, s1, s2, lr, gmask);
  k2_att_pv<<<dim3(128, 2, 8), 256, 0, stream>>>(gmask, WhT, s1, s2, lr, pp0, pp1, att);
  k3_elu   <<<dim3(1024),      256, 0, stream>>>(pp0, pp1, hout);
}